// Round 17
// baseline (108.022 us; speedup 1.0000x reference)
//
#include <hip/hip_runtime.h>
#include <hip/hip_bf16.h>

typedef __bf16 bf16;
typedef __bf16 bf16x4 __attribute__((ext_vector_type(4)));
typedef __bf16 bf16x8 __attribute__((ext_vector_type(8)));
typedef float  f32x4  __attribute__((ext_vector_type(4)));

#define MFMA(a, b, c) __builtin_amdgcn_mfma_f32_16x16x32_bf16((a), (b), (c), 0, 0, 0)

__device__ __forceinline__ void async_ld16(void* l, const void* g) {
    __builtin_amdgcn_global_load_lds(
        (const __attribute__((address_space(1))) void*)g,
        (__attribute__((address_space(3))) void*)l, 16, 0, 0);
}

// ---------------- fused prep kernel (unchanged from R15) ----------------
__global__ __launch_bounds__(256) void prep_fused(const float* __restrict__ x,
                                                  const float* __restrict__ Wattn,
                                                  const float* __restrict__ Wproj,
                                                  const float* __restrict__ ct,
                                                  bf16* __restrict__ xb,
                                                  bf16* __restrict__ Wa_t,
                                                  bf16* __restrict__ Wp_t,
                                                  bf16* __restrict__ yb,
                                                  bf16* __restrict__ qb,
                                                  bf16* __restrict__ kbuf,
                                                  bf16* __restrict__ vtb,
                                                  unsigned char* __restrict__ idx) {
    const int bid = blockIdx.x;
    const int tid = threadIdx.x;
    if (bid < 2048) {
        const float4* src = (const float4*)x;
        ushort4* dst = (ushort4*)xb;
        for (int i = bid * 256 + tid; i < 1024000; i += 2048 * 256) {
            float4 v = src[i];
            ushort4 o;
            o.x = (unsigned short)__bfloat16_as_ushort(__float2bfloat16(v.x));
            o.y = (unsigned short)__bfloat16_as_ushort(__float2bfloat16(v.y));
            o.z = (unsigned short)__bfloat16_as_ushort(__float2bfloat16(v.z));
            o.w = (unsigned short)__bfloat16_as_ushort(__float2bfloat16(v.w));
            dst[i] = o;
        }
    } else if (bid < 5120) {
        int i = (bid - 2048) * 256 + tid;
        int k = i / 1536, n = i - k * 1536;
        Wa_t[n * 512 + k] = (bf16)Wattn[i];
    } else if (bid < 6144) {
        int i = (bid - 5120) * 256 + tid;
        int k = i >> 9, n = i & 511;
        Wp_t[n * 512 + k] = (bf16)Wproj[i];
    } else if (bid < 6304) {
        const bf16x8 z8 = {(bf16)0.f, (bf16)0.f, (bf16)0.f, (bf16)0.f,
                           (bf16)0.f, (bf16)0.f, (bf16)0.f, (bf16)0.f};
        const bf16x4 z4 = {(bf16)0.f, (bf16)0.f, (bf16)0.f, (bf16)0.f};
        int i = (bid - 6144) * 256 + tid;
        if (i < 4096) {
            *(bf16x8*)(xb + (size_t)8000 * 512 + i * 8) = z8;
        } else if (i < 8192) {
            *(bf16x8*)(yb + (size_t)8000 * 512 + (i - 4096) * 8) = z8;
        } else if (i < 20480) {
            int c = i - 8192;
            int bh = c / 96, rem = c % 96;
            int t = 500 + rem / 8, d8 = rem % 8;
            *(bf16x8*)(qb + (((size_t)bh * 512 + t) * 64) + d8 * 8) = z8;
        } else if (i < 32768) {
            int c = i - 20480;
            int bh = c / 96, rem = c % 96;
            int t = 500 + rem / 8, d8 = rem % 8;
            *(bf16x8*)(kbuf + (((size_t)bh * 512 + t) * 64) + d8 * 8) = z8;
        } else if (i < 40960) {
            int w = i - 32768;
            int bh = w >> 6, d = w & 63;
            bf16* base = vtb + ((size_t)bh * 64 + d) * 512 + 500;
            *(bf16x4*)base = z4;
            *(bf16x8*)(base + 4) = z8;
        }
    } else {
        int bt = bid - 6304;
        int b = bt >> 9, t = bt & 511;
        const bool tv = (t < 500);
        float ctx = 0.f, cty = 0.f;
        if (tv) {
            ctx = ct[(b * 500 + t) * 2];
            cty = ct[(b * 500 + t) * 2 + 1];
        }
        int s0 = tid * 2;
        unsigned char v[2];
#pragma unroll
        for (int j = 0; j < 2; j++) {
            int s = s0 + j;
            unsigned char rr = 63;
            if (tv && s < 500) {
                float dx = ctx - ct[(b * 500 + s) * 2];
                float dy = cty - ct[(b * 500 + s) * 2 + 1];
                float dist = truncf(sqrtf(dx * dx + dy * dy) / 12.0f);
                int bi;
                if (dist <= 12.0f) {
                    bi = (int)dist;
                } else {
                    float lb = fminf(24.0f, rintf(12.0f + (logf(dist / 12.0f) * (1.0f / 2.0794415416798357f)) * 12.0f));
                    bi = (int)lb;
                }
                rr = (unsigned char)(bi + 24);
            }
            v[j] = rr;
        }
        uchar2 o2; o2.x = v[0]; o2.y = v[1];
        *(uchar2*)(idx + ((size_t)bt) * 512 + s0) = o2;
    }
}

// ---------------- double-buffered pipelined 128-tile GEMM (unchanged) ----------------
template<int BN, int WGM, int WGN, int EPI>
__global__ __launch_bounds__(256) void gemm128(const bf16* __restrict__ A,
                                               const bf16* __restrict__ Bt,
                                               const float* __restrict__ bias,
                                               bf16* __restrict__ o_q,
                                               bf16* __restrict__ o_k,
                                               bf16* __restrict__ o_v,
                                               float* __restrict__ o_f) {
    constexpr int BM = 128, BK = 64, K = 512, NT = K / BK;
    constexpr int WM = BM / (WGM * 16);
    constexpr int WN = BN / (WGN * 16);
    constexpr int NA = BM * 8 / 256;
    constexpr int NB = BN * 8 / 256;
    constexpr int LD = (BM + BN) * BK;

    __shared__ __align__(1024) bf16 lds[2 * LD];

    const int lane = threadIdx.x & 63;
    const int wave = threadIdx.x >> 6;

    const int gdx = gridDim.x;
    const int nwg = gdx * gridDim.y;
    const int bid = blockIdx.y * gdx + blockIdx.x;
    const int qq = nwg >> 3, rr = nwg & 7;
    const int xcd = bid & 7, jj = bid >> 3;
    const int wg = (xcd < rr ? xcd * (qq + 1) : rr * (qq + 1) + (xcd - rr) * qq) + jj;
    const int m0 = (wg / gdx) * BM;
    const int n0 = (wg % gdx) * BN;

    const int wr = wave / WGN, wc = wave % WGN;
    const int r = lane & 15, g = lane >> 4;

    const bf16* pa[NA];
    const bf16* pb[NB];
    int loA[NA], loB[NB];
#pragma unroll
    for (int i = 0; i < NA; i++) {
        int cbase = i * 256 + wave * 64;
        int c = cbase + lane;
        int row = c >> 3, cb = (c & 7) * 16;
        pa[i] = A + (size_t)(m0 + row) * K + ((cb ^ ((row & 7) << 4)) >> 1);
        loA[i] = cbase * 8;
    }
#pragma unroll
    for (int i = 0; i < NB; i++) {
        int cbase = i * 256 + wave * 64;
        int c = cbase + lane;
        int row = c >> 3, cb = (c & 7) * 16;
        pb[i] = Bt + (size_t)(n0 + row) * K + ((cb ^ ((row & 7) << 4)) >> 1);
        loB[i] = cbase * 8;
    }

    f32x4 acc[WM][WN];
#pragma unroll
    for (int i = 0; i < WM; i++)
#pragma unroll
        for (int j = 0; j < WN; j++) acc[i][j] = (f32x4){0.f, 0.f, 0.f, 0.f};

    auto stage = [&](int buf, int kt) {
        bf16* la = lds + buf * LD;
        bf16* lb = la + BM * BK;
#pragma unroll
        for (int i = 0; i < NA; i++) async_ld16(la + loA[i], pa[i] + kt);
#pragma unroll
        for (int i = 0; i < NB; i++) async_ld16(lb + loB[i], pb[i] + kt);
    };

    stage(0, 0);
    int cur = 0;
#pragma unroll
    for (int t = 0; t < NT; t++) {
        if (t + 1 < NT) {
            stage(cur ^ 1, (t + 1) * BK);
            asm volatile("s_waitcnt vmcnt(%0)" ::"i"(NA + NB) : "memory");
        } else {
            asm volatile("s_waitcnt vmcnt(0)" ::: "memory");
        }
        __builtin_amdgcn_s_barrier();
        const bf16* la = lds + cur * LD;
        const bf16* lb = la + BM * BK;
#pragma unroll
        for (int kh = 0; kh < 2; kh++) {
            const int cb = kh * 64 + g * 16;
            bf16x8 af[WM], bfv[WN];
#pragma unroll
            for (int mf = 0; mf < WM; mf++) {
                int fr = wr * WM * 16 + mf * 16 + r;
                af[mf] = *(const bf16x8*)&la[fr * 64 + ((cb ^ ((fr & 7) << 4)) >> 1)];
            }
#pragma unroll
            for (int nf = 0; nf < WN; nf++) {
                int fr = wc * WN * 16 + nf * 16 + r;
                bfv[nf] = *(const bf16x8*)&lb[fr * 64 + ((cb ^ ((fr & 7) << 4)) >> 1)];
            }
#pragma unroll
            for (int mf = 0; mf < WM; mf++)
#pragma unroll
                for (int nf = 0; nf < WN; nf++)
                    acc[mf][nf] = MFMA(af[mf], bfv[nf], acc[mf][nf]);
        }
        asm volatile("" ::: "memory");
        __builtin_amdgcn_s_barrier();
        cur ^= 1;
    }

    if (EPI == 0) {
        const bool isv = (n0 >= 1024);
        bf16* tile = lds;
#pragma unroll
        for (int mf = 0; mf < WM; mf++)
#pragma unroll
            for (int nf = 0; nf < WN; nf++) {
                int nl = wc * WN * 16 + nf * 16 + r;
                float bv = bias[n0 + nl];
#pragma unroll
                for (int reg = 0; reg < 4; reg++) {
                    int ml = wr * WM * 16 + mf * 16 + g * 4 + reg;
                    bf16 val = (bf16)(acc[mf][nf][reg] + bv);
                    int byte = isv ? (nl * 256 + ((ml * 2) ^ ((nl & 7) << 4)))
                                   : (ml * 256 + ((nl * 2) ^ ((ml & 7) << 4)));
                    tile[byte >> 1] = val;
                }
            }
        __syncthreads();
        const int h0 = (n0 & 511) >> 6;
        if (!isv) {
            bf16* dst = (n0 < 512) ? o_q : o_k;
#pragma unroll
            for (int j = 0; j < 8; j++) {
                int seg = wave * 64 + j * 8 + (lane >> 3);
                int ml = seg >> 1, hp = seg & 1;
                int m = m0 + ml;
                if (m < 8000) {
                    int cb2 = (hp * 128 + (lane & 7) * 16) ^ ((ml & 7) << 4);
                    bf16x8 v8 = *(const bf16x8*)&tile[(ml * 256 + cb2) >> 1];
                    int b = m / 500, t = m - b * 500;
                    *(bf16x8*)&dst[(((size_t)(b * 8 + h0 + hp)) * 512 + t) * 64 + (lane & 7) * 8] = v8;
                }
            }
        } else {
#pragma unroll
            for (int j = 0; j < 8; j++) {
                int seg = wave * 64 + j * 8 + (lane >> 3);
                int nl = seg >> 1, mh = seg & 1;
                int mloc = mh * 64 + (lane & 7) * 8;
                int m = m0 + mloc;
                if (m < 8000) {
                    int cb2 = (mh * 128 + (lane & 7) * 16) ^ ((nl & 7) << 4);
                    bf16x8 v8 = *(const bf16x8*)&tile[(nl * 256 + cb2) >> 1];
                    int h = h0 + (nl >> 6), d = nl & 63;
                    int b0 = m / 500, b1 = (m + 7) / 500;
                    if (b0 == b1) {
                        int t = m - b0 * 500;
                        bf16* p = o_v + (((size_t)(b0 * 8 + h)) * 64 + d) * 512 + t;
                        if ((t & 7) == 0) {
                            *(bf16x8*)p = v8;
                        } else {
                            bf16x4 lo = {v8[0], v8[1], v8[2], v8[3]};
                            bf16x4 hi = {v8[4], v8[5], v8[6], v8[7]};
                            *(bf16x4*)p = lo;
                            *(bf16x4*)(p + 4) = hi;
                        }
                    } else {
#pragma unroll
                        for (int i = 0; i < 8; i++) {
                            int mi = m + i;
                            int bb = mi / 500, tt = mi - bb * 500;
                            o_v[(((size_t)(bb * 8 + h)) * 64 + d) * 512 + tt] = v8[i];
                        }
                    }
                }
            }
        }
    } else {
#pragma unroll
        for (int mf = 0; mf < WM; mf++) {
#pragma unroll
            for (int nf = 0; nf < WN; nf++) {
                int n = n0 + wc * WN * 16 + nf * 16 + r;
                float bv = bias[n];
#pragma unroll
                for (int reg = 0; reg < 4; reg++) {
                    int m = m0 + wr * WM * 16 + mf * 16 + g * 4 + reg;
                    if (m < 8000) o_f[(size_t)m * 512 + n] = acc[mf][nf][reg] + bv;
                }
            }
        }
    }
}

// ---------------- fused attention: R15 base + V in registers (K stays in LDS) ----------------
// Single-variable delta from the best config (R15/R14): VT removed from LDS; V
// fragments load global->VGPR right after the barrier (issued early, consumed at
// PV after QK+softmax ~250cy). Removes 8 of 28 LDS ops/wave-tile + halves staging.
// K dbuf + reg-idx + 1-barrier cadence unchanged. No launch_bounds min-wave clamp
// (grid caps at 2 blocks/CU): ~160 VGPR fits without spill (R16's failure mode).
__global__ __launch_bounds__(256) void attn_kernel(const bf16* __restrict__ qb,
                                                   const bf16* __restrict__ kbuf,
                                                   const bf16* __restrict__ vtb,
                                                   const unsigned char* __restrict__ idxg,
                                                   const float* __restrict__ lut,
                                                   bf16* __restrict__ yb) {
    __shared__ __align__(1024) bf16 KT[2][4096];  // [64 s][64 k] swizzled
    __shared__ float lut_s[64];
    __shared__ __align__(16) bf16 P[4][2][16][72];

    const int lane = threadIdx.x & 63;
    const int wave = threadIdx.x >> 6;
    const int tid = threadIdx.x;
    // XCD-chunked swizzle (512 = 8 x 64 exact)
    const int bid0 = blockIdx.x;
    const int wg = (bid0 & 7) * 64 + (bid0 >> 3);
    const int bh = wg >> 2;
    const int qt = wg & 3;
    const int b = bh >> 3;
    const int h = bh & 7;

    if (tid < 64)
        lut_s[tid] = (tid < 49) ? lut[h * 49 + tid] * 1.4426950408889634f : -1e30f;

    const int r = lane & 15;
    const int g = lane >> 4;
    const int ko = g << 3;
    const int rowbase = qt * 128 + wave * 32;

    // Q: 2 chunks x 2 k-halves
    bf16x8 qf[2][2];
#pragma unroll
    for (int c = 0; c < 2; c++) {
        const bf16* qp = qb + ((size_t)bh * 512 + rowbase + c * 16 + r) * 64 + ko;
        qf[c][0] = *(const bf16x8*)qp;
        qf[c][1] = *(const bf16x8*)(qp + 32);
    }

    const bf16* kbb = kbuf + (size_t)bh * 512 * 64;
    const bf16* vbb = vtb + (size_t)bh * 64 * 512;
    const unsigned char* ip0 = idxg + ((size_t)b * 512 + rowbase + r) * 512;
    const unsigned char* ip1 = ip0 + (size_t)16 * 512;

    // K staging addresses (tile-invariant), pre-swizzled source
    const int c0 = tid, c1 = 256 + tid;
    const int kr0 = c0 >> 3, ks0 = (c0 & 7) * 16;
    const int kr1 = c1 >> 3, ks1 = (c1 & 7) * 16;
    const bf16* ksrc0 = kbb + (size_t)kr0 * 64 + ((ks0 ^ ((kr0 & 7) << 4)) >> 1);
    const bf16* ksrc1 = kbb + (size_t)kr1 * 64 + ((ks1 ^ ((kr1 & 7) << 4)) >> 1);

    auto stage = [&](int buf, int s0) {  // 2 loads/thread (K only)
        async_ld16(&KT[buf][c0 * 8], ksrc0 + (size_t)s0 * 64);
        async_ld16(&KT[buf][c1 * 8], ksrc1 + (size_t)s0 * 64);
    };

    // V fragment base pointers (tile-invariant)
    const bf16* vp[4];
#pragma unroll
    for (int nf = 0; nf < 4; nf++) vp[nf] = vbb + (size_t)(nf * 16 + r) * 512 + ko;

    // idx register double-buffer
    unsigned int idb[2][2][4];
    auto ldidx = [&](int par, int s0) {
#pragma unroll
        for (int nf = 0; nf < 4; nf++) {
            idb[par][0][nf] = *(const unsigned int*)(ip0 + s0 + nf * 16 + (g << 2));
            idb[par][1][nf] = *(const unsigned int*)(ip1 + s0 + nf * 16 + (g << 2));
        }
    };

    f32x4 o[2][4];
#pragma unroll
    for (int c = 0; c < 2; c++)
#pragma unroll
        for (int i = 0; i < 4; i++) o[c][i] = (f32x4){0.f, 0.f, 0.f, 0.f};
    float lsum[2] = {0.f, 0.f};

    const float QS = 0.125f * 1.4426950408889634f;

    stage(0, 0);
    ldidx(0, 0);
#pragma unroll
    for (int ti = 0; ti < 8; ti++) {
        const int buf = ti & 1;
        const int s0 = ti * 64;
        asm volatile("s_waitcnt vmcnt(0)" ::: "memory");
        __builtin_amdgcn_s_barrier();
        // V(current): issue first (consumed at PV after QK+softmax)
        bf16x8 vf[4][2];
#pragma unroll
        for (int nf = 0; nf < 4; nf++) {
            vf[nf][0] = *(const bf16x8*)(vp[nf] + s0);
            vf[nf][1] = *(const bf16x8*)(vp[nf] + s0 + 32);
        }
        if (ti < 7) {
            stage(buf ^ 1, s0 + 64);
            ldidx((ti + 1) & 1, s0 + 64);
        }
        // QK^T from LDS (K fragments shared by both chunks)
        f32x4 sa[2][4];
        __builtin_amdgcn_s_setprio(1);
#pragma unroll
        for (int nf = 0; nf < 4; nf++) {
            const int row = nf * 16 + r;
            const int swz = (row & 7) << 4;
            bf16x8 kf0 = *(const bf16x8*)&KT[buf][row * 64 + (((g * 16) ^ swz) >> 1)];
            bf16x8 kf1 = *(const bf16x8*)&KT[buf][row * 64 + (((g * 16 + 64) ^ swz) >> 1)];
            sa[0][nf] = MFMA(kf0, qf[0][0], ((f32x4){0.f, 0.f, 0.f, 0.f}));
            sa[0][nf] = MFMA(kf1, qf[0][1], sa[0][nf]);
            sa[1][nf] = MFMA(kf0, qf[1][0], ((f32x4){0.f, 0.f, 0.f, 0.f}));
            sa[1][nf] = MFMA(kf1, qf[1][1], sa[1][nf]);
        }
        __builtin_amdgcn_s_setprio(0);
        // softmax (no-max): p = exp2(qk*QS + biasL2); sentinel 63 -> 0
#pragma unroll
        for (int c = 0; c < 2; c++) {
            float ts = 0.f;
#pragma unroll
            for (int nf = 0; nf < 4; nf++) {
                unsigned int u = idb[ti & 1][c][nf];
                float p0 = exp2f(fmaf(sa[c][nf][0], QS, lut_s[u & 255]));
                float p1 = exp2f(fmaf(sa[c][nf][1], QS, lut_s[(u >> 8) & 255]));
                float p2 = exp2f(fmaf(sa[c][nf][2], QS, lut_s[(u >> 16) & 255]));
                float p3 = exp2f(fmaf(sa[c][nf][3], QS, lut_s[u >> 24]));
                ts += (p0 + p1) + (p2 + p3);
                bf16x4 pk = {(bf16)p0, (bf16)p1, (bf16)p2, (bf16)p3};
                *(bf16x4*)&P[wave][c][r][nf * 16 + (g << 2)] = pk;
            }
            lsum[c] += ts;
        }
        // PV (V from registers; P round-trip wave-private)
        bf16x8 pf00 = *(const bf16x8*)&P[wave][0][r][ko];
        bf16x8 pf01 = *(const bf16x8*)&P[wave][0][r][32 + ko];
        bf16x8 pf10 = *(const bf16x8*)&P[wave][1][r][ko];
        bf16x8 pf11 = *(const bf16x8*)&P[wave][1][r][32 + ko];
        __builtin_amdgcn_s_setprio(1);
#pragma unroll
        for (int nf = 0; nf < 4; nf++) {
            o[0][nf] = MFMA(pf00, vf[nf][0], o[0][nf]);
            o[0][nf] = MFMA(pf01, vf[nf][1], o[0][nf]);
            o[1][nf] = MFMA(pf10, vf[nf][0], o[1][nf]);
            o[1][nf] = MFMA(pf11, vf[nf][1], o[1][nf]);
        }
        __builtin_amdgcn_s_setprio(0);
    }
    // epilogue: per-chunk row sums (2 shfl each) + normalized store
#pragma unroll
    for (int c = 0; c < 2; c++) {
        float ls = lsum[c];
        ls += __shfl_xor(ls, 16);
        ls += __shfl_xor(ls, 32);
        float invl = 1.0f / ls;
#pragma unroll
        for (int reg = 0; reg < 4; reg++) {
            float il = __shfl(invl, (g << 2) + reg);
            int t = rowbase + c * 16 + (g << 2) + reg;
            if (t < 500) {
                bf16* yp = yb + ((size_t)(b * 500 + t)) * 512 + h * 64;
#pragma unroll
                for (int nf = 0; nf < 4; nf++) yp[nf * 16 + r] = (bf16)(o[c][nf][reg] * il);
            }
        }
    }
}

// ---------------- launch ----------------
extern "C" void kernel_launch(void* const* d_in, const int* in_sizes, int n_in,
                              void* d_out, int out_size, void* d_ws, size_t ws_size,
                              hipStream_t stream) {
    const float* x     = (const float*)d_in[0];
    const float* ct    = (const float*)d_in[1];
    const float* Wattn = (const float*)d_in[2];
    const float* battn = (const float*)d_in[3];
    const float* Wproj = (const float*)d_in[4];
    const float* bproj = (const float*)d_in[5];
    const float* lut   = (const float*)d_in[6];
    float* out = (float*)d_out;

    char* w = (char*)d_ws;
    bf16* xb   = (bf16*)w;                w += (size_t)8064 * 512 * 2;
    bf16* Wa_t = (bf16*)w;                w += (size_t)1536 * 512 * 2;
    bf16* Wp_t = (bf16*)w;                w += (size_t)512 * 512 * 2;
    bf16* qb   = (bf16*)w;                w += (size_t)16 * 8 * 512 * 64 * 2;
    bf16* kbuf = (bf16*)w;                w += (size_t)16 * 8 * 512 * 64 * 2;
    bf16* vtb  = (bf16*)w;                w += (size_t)16 * 8 * 64 * 512 * 2;
    unsigned char* idxb = (unsigned char*)w; w += (size_t)16 * 512 * 512;
    bf16* yb   = (bf16*)w;                w += (size_t)8064 * 512 * 2;

    prep_fused<<<dim3(14496), 256, 0, stream>>>(x, Wattn, Wproj, ct,
                                                xb, Wa_t, Wp_t, yb, qb, kbuf, vtb, idxb);

    gemm128<128, 2, 2, 0><<<dim3(12, 63), 256, 0, stream>>>(xb, Wa_t, battn, qb, kbuf, vtb, nullptr);

    attn_kernel<<<dim3(512), 256, 0, stream>>>(qb, kbuf, vtb, idxb, lut, yb);

    gemm128<64, 4, 1, 1><<<dim3(8, 63), 256, 0, stream>>>(yb, Wp_t, bproj, nullptr, nullptr, nullptr, out);
}

// Round 18
// 80.174 us; speedup vs baseline: 1.3474x; 1.3474x over previous
//
#include <hip/hip_runtime.h>
#include <hip/hip_bf16.h>

typedef __bf16 bf16;
typedef __bf16 bf16x4 __attribute__((ext_vector_type(4)));
typedef __bf16 bf16x8 __attribute__((ext_vector_type(8)));
typedef float  f32x4  __attribute__((ext_vector_type(4)));

#define MFMA(a, b, c) __builtin_amdgcn_mfma_f32_16x16x32_bf16((a), (b), (c), 0, 0, 0)

__device__ __forceinline__ void async_ld16(void* l, const void* g) {
    __builtin_amdgcn_global_load_lds(
        (const __attribute__((address_space(1))) void*)g,
        (__attribute__((address_space(3))) void*)l, 16, 0, 0);
}

// ---------------- fused prep kernel ----------------
__global__ __launch_bounds__(256) void prep_fused(const float* __restrict__ x,
                                                  const float* __restrict__ Wattn,
                                                  const float* __restrict__ Wproj,
                                                  const float* __restrict__ ct,
                                                  bf16* __restrict__ xb,
                                                  bf16* __restrict__ Wa_t,
                                                  bf16* __restrict__ Wp_t,
                                                  bf16* __restrict__ yb,
                                                  bf16* __restrict__ qb,
                                                  bf16* __restrict__ kbuf,
                                                  bf16* __restrict__ vtb,
                                                  unsigned char* __restrict__ idx) {
    const int bid = blockIdx.x;
    const int tid = threadIdx.x;
    if (bid < 2048) {
        const float4* src = (const float4*)x;
        ushort4* dst = (ushort4*)xb;
        for (int i = bid * 256 + tid; i < 1024000; i += 2048 * 256) {
            float4 v = src[i];
            ushort4 o;
            o.x = (unsigned short)__bfloat16_as_ushort(__float2bfloat16(v.x));
            o.y = (unsigned short)__bfloat16_as_ushort(__float2bfloat16(v.y));
            o.z = (unsigned short)__bfloat16_as_ushort(__float2bfloat16(v.z));
            o.w = (unsigned short)__bfloat16_as_ushort(__float2bfloat16(v.w));
            dst[i] = o;
        }
    } else if (bid < 5120) {
        int i = (bid - 2048) * 256 + tid;
        int k = i / 1536, n = i - k * 1536;
        Wa_t[n * 512 + k] = (bf16)Wattn[i];
    } else if (bid < 6144) {
        int i = (bid - 5120) * 256 + tid;
        int k = i >> 9, n = i & 511;
        Wp_t[n * 512 + k] = (bf16)Wproj[i];
    } else if (bid < 6304) {
        const bf16x8 z8 = {(bf16)0.f, (bf16)0.f, (bf16)0.f, (bf16)0.f,
                           (bf16)0.f, (bf16)0.f, (bf16)0.f, (bf16)0.f};
        const bf16x4 z4 = {(bf16)0.f, (bf16)0.f, (bf16)0.f, (bf16)0.f};
        int i = (bid - 6144) * 256 + tid;
        if (i < 4096) {
            *(bf16x8*)(xb + (size_t)8000 * 512 + i * 8) = z8;
        } else if (i < 8192) {
            *(bf16x8*)(yb + (size_t)8000 * 512 + (i - 4096) * 8) = z8;
        } else if (i < 20480) {
            int c = i - 8192;
            int bh = c / 96, rem = c % 96;
            int t = 500 + rem / 8, d8 = rem % 8;
            *(bf16x8*)(qb + (((size_t)bh * 512 + t) * 64) + d8 * 8) = z8;
        } else if (i < 32768) {
            int c = i - 20480;
            int bh = c / 96, rem = c % 96;
            int t = 500 + rem / 8, d8 = rem % 8;
            *(bf16x8*)(kbuf + (((size_t)bh * 512 + t) * 64) + d8 * 8) = z8;
        } else if (i < 40960) {
            int w = i - 32768;
            int bh = w >> 6, d = w & 63;
            bf16* base = vtb + ((size_t)bh * 64 + d) * 512 + 500;
            *(bf16x4*)base = z4;
            *(bf16x8*)(base + 4) = z8;
        }
    } else {
        int bt = bid - 6304;
        int b = bt >> 9, t = bt & 511;
        const bool tv = (t < 500);
        float ctx = 0.f, cty = 0.f;
        if (tv) {
            ctx = ct[(b * 500 + t) * 2];
            cty = ct[(b * 500 + t) * 2 + 1];
        }
        int s0 = tid * 2;
        unsigned char v[2];
#pragma unroll
        for (int j = 0; j < 2; j++) {
            int s = s0 + j;
            unsigned char rr = 63;
            if (tv && s < 500) {
                float dx = ctx - ct[(b * 500 + s) * 2];
                float dy = cty - ct[(b * 500 + s) * 2 + 1];
                float dist = truncf(sqrtf(dx * dx + dy * dy) / 12.0f);
                int bi;
                if (dist <= 12.0f) {
                    bi = (int)dist;
                } else {
                    float lb = fminf(24.0f, rintf(12.0f + (logf(dist / 12.0f) * (1.0f / 2.0794415416798357f)) * 12.0f));
                    bi = (int)lb;
                }
                rr = (unsigned char)(bi + 24);
            }
            v[j] = rr;
        }
        uchar2 o2; o2.x = v[0]; o2.y = v[1];
        *(uchar2*)(idx + ((size_t)bt) * 512 + s0) = o2;
    }
}

// ---------------- double-buffered pipelined 128-tile GEMM ----------------
template<int BN, int WGM, int WGN, int EPI>
__global__ __launch_bounds__(256) void gemm128(const bf16* __restrict__ A,
                                               const bf16* __restrict__ Bt,
                                               const float* __restrict__ bias,
                                               bf16* __restrict__ o_q,
                                               bf16* __restrict__ o_k,
                                               bf16* __restrict__ o_v,
                                               float* __restrict__ o_f) {
    constexpr int BM = 128, BK = 64, K = 512, NT = K / BK;
    constexpr int WM = BM / (WGM * 16);
    constexpr int WN = BN / (WGN * 16);
    constexpr int NA = BM * 8 / 256;
    constexpr int NB = BN * 8 / 256;
    constexpr int LD = (BM + BN) * BK;

    __shared__ __align__(1024) bf16 lds[2 * LD];

    const int lane = threadIdx.x & 63;
    const int wave = threadIdx.x >> 6;

    const int gdx = gridDim.x;
    const int nwg = gdx * gridDim.y;
    const int bid = blockIdx.y * gdx + blockIdx.x;
    const int qq = nwg >> 3, rr = nwg & 7;
    const int xcd = bid & 7, jj = bid >> 3;
    const int wg = (xcd < rr ? xcd * (qq + 1) : rr * (qq + 1) + (xcd - rr) * qq) + jj;
    const int m0 = (wg / gdx) * BM;
    const int n0 = (wg % gdx) * BN;

    const int wr = wave / WGN, wc = wave % WGN;
    const int r = lane & 15, g = lane >> 4;

    const bf16* pa[NA];
    const bf16* pb[NB];
    int loA[NA], loB[NB];
#pragma unroll
    for (int i = 0; i < NA; i++) {
        int cbase = i * 256 + wave * 64;
        int c = cbase + lane;
        int row = c >> 3, cb = (c & 7) * 16;
        pa[i] = A + (size_t)(m0 + row) * K + ((cb ^ ((row & 7) << 4)) >> 1);
        loA[i] = cbase * 8;
    }
#pragma unroll
    for (int i = 0; i < NB; i++) {
        int cbase = i * 256 + wave * 64;
        int c = cbase + lane;
        int row = c >> 3, cb = (c & 7) * 16;
        pb[i] = Bt + (size_t)(n0 + row) * K + ((cb ^ ((row & 7) << 4)) >> 1);
        loB[i] = cbase * 8;
    }

    f32x4 acc[WM][WN];
#pragma unroll
    for (int i = 0; i < WM; i++)
#pragma unroll
        for (int j = 0; j < WN; j++) acc[i][j] = (f32x4){0.f, 0.f, 0.f, 0.f};

    auto stage = [&](int buf, int kt) {
        bf16* la = lds + buf * LD;
        bf16* lb = la + BM * BK;
#pragma unroll
        for (int i = 0; i < NA; i++) async_ld16(la + loA[i], pa[i] + kt);
#pragma unroll
        for (int i = 0; i < NB; i++) async_ld16(lb + loB[i], pb[i] + kt);
    };

    stage(0, 0);
    int cur = 0;
#pragma unroll
    for (int t = 0; t < NT; t++) {
        if (t + 1 < NT) {
            stage(cur ^ 1, (t + 1) * BK);
            asm volatile("s_waitcnt vmcnt(%0)" ::"i"(NA + NB) : "memory");
        } else {
            asm volatile("s_waitcnt vmcnt(0)" ::: "memory");
        }
        __builtin_amdgcn_s_barrier();
        const bf16* la = lds + cur * LD;
        const bf16* lb = la + BM * BK;
#pragma unroll
        for (int kh = 0; kh < 2; kh++) {
            const int cb = kh * 64 + g * 16;
            bf16x8 af[WM], bfv[WN];
#pragma unroll
            for (int mf = 0; mf < WM; mf++) {
                int fr = wr * WM * 16 + mf * 16 + r;
                af[mf] = *(const bf16x8*)&la[fr * 64 + ((cb ^ ((fr & 7) << 4)) >> 1)];
            }
#pragma unroll
            for (int nf = 0; nf < WN; nf++) {
                int fr = wc * WN * 16 + nf * 16 + r;
                bfv[nf] = *(const bf16x8*)&lb[fr * 64 + ((cb ^ ((fr & 7) << 4)) >> 1)];
            }
#pragma unroll
            for (int mf = 0; mf < WM; mf++)
#pragma unroll
                for (int nf = 0; nf < WN; nf++)
                    acc[mf][nf] = MFMA(af[mf], bfv[nf], acc[mf][nf]);
        }
        asm volatile("" ::: "memory");
        __builtin_amdgcn_s_barrier();
        cur ^= 1;
    }

    if (EPI == 0) {
        const bool isv = (n0 >= 1024);
        bf16* tile = lds;
#pragma unroll
        for (int mf = 0; mf < WM; mf++)
#pragma unroll
            for (int nf = 0; nf < WN; nf++) {
                int nl = wc * WN * 16 + nf * 16 + r;
                float bv = bias[n0 + nl];
#pragma unroll
                for (int reg = 0; reg < 4; reg++) {
                    int ml = wr * WM * 16 + mf * 16 + g * 4 + reg;
                    bf16 val = (bf16)(acc[mf][nf][reg] + bv);
                    int byte = isv ? (nl * 256 + ((ml * 2) ^ ((nl & 7) << 4)))
                                   : (ml * 256 + ((nl * 2) ^ ((ml & 7) << 4)));
                    tile[byte >> 1] = val;
                }
            }
        __syncthreads();
        const int h0 = (n0 & 511) >> 6;
        if (!isv) {
            bf16* dst = (n0 < 512) ? o_q : o_k;
#pragma unroll
            for (int j = 0; j < 8; j++) {
                int seg = wave * 64 + j * 8 + (lane >> 3);
                int ml = seg >> 1, hp = seg & 1;
                int m = m0 + ml;
                if (m < 8000) {
                    int cb2 = (hp * 128 + (lane & 7) * 16) ^ ((ml & 7) << 4);
                    bf16x8 v8 = *(const bf16x8*)&tile[(ml * 256 + cb2) >> 1];
                    int b = m / 500, t = m - b * 500;
                    *(bf16x8*)&dst[(((size_t)(b * 8 + h0 + hp)) * 512 + t) * 64 + (lane & 7) * 8] = v8;
                }
            }
        } else {
#pragma unroll
            for (int j = 0; j < 8; j++) {
                int seg = wave * 64 + j * 8 + (lane >> 3);
                int nl = seg >> 1, mh = seg & 1;
                int mloc = mh * 64 + (lane & 7) * 8;
                int m = m0 + mloc;
                if (m < 8000) {
                    int cb2 = (mh * 128 + (lane & 7) * 16) ^ ((nl & 7) << 4);
                    bf16x8 v8 = *(const bf16x8*)&tile[(nl * 256 + cb2) >> 1];
                    int h = h0 + (nl >> 6), d = nl & 63;
                    int b0 = m / 500, b1 = (m + 7) / 500;
                    if (b0 == b1) {
                        int t = m - b0 * 500;
                        bf16* p = o_v + (((size_t)(b0 * 8 + h)) * 64 + d) * 512 + t;
                        if ((t & 7) == 0) {
                            *(bf16x8*)p = v8;
                        } else {
                            bf16x4 lo = {v8[0], v8[1], v8[2], v8[3]};
                            bf16x4 hi = {v8[4], v8[5], v8[6], v8[7]};
                            *(bf16x4*)p = lo;
                            *(bf16x4*)(p + 4) = hi;
                        }
                    } else {
#pragma unroll
                        for (int i = 0; i < 8; i++) {
                            int mi = m + i;
                            int bb = mi / 500, tt = mi - bb * 500;
                            o_v[(((size_t)(bb * 8 + h)) * 64 + d) * 512 + tt] = v8[i];
                        }
                    }
                }
            }
        }
    } else {
#pragma unroll
        for (int mf = 0; mf < WM; mf++) {
#pragma unroll
            for (int nf = 0; nf < WN; nf++) {
                int n = n0 + wc * WN * 16 + nf * 16 + r;
                float bv = bias[n];
#pragma unroll
                for (int reg = 0; reg < 4; reg++) {
                    int m = m0 + wr * WM * 16 + mf * 16 + g * 4 + reg;
                    if (m < 8000) o_f[(size_t)m * 512 + n] = acc[mf][nf][reg] + bv;
                }
            }
        }
    }
}

// ---------------- fused attention (R14/R15 best config: K+V LDS dbuf, reg idx) ----------------
__global__ __launch_bounds__(256) void attn_kernel(const bf16* __restrict__ qb,
                                                   const bf16* __restrict__ kbuf,
                                                   const bf16* __restrict__ vtb,
                                                   const unsigned char* __restrict__ idxg,
                                                   const float* __restrict__ lut,
                                                   bf16* __restrict__ yb) {
    __shared__ __align__(1024) bf16 KT[2][4096];  // [64 s][64 k] swizzled
    __shared__ __align__(1024) bf16 VT[2][4096];  // [64 d][64 s] swizzled
    __shared__ float lut_s[64];
    __shared__ __align__(16) bf16 P[4][2][16][72];

    const int lane = threadIdx.x & 63;
    const int wave = threadIdx.x >> 6;
    const int tid = threadIdx.x;
    const int bid0 = blockIdx.x;
    const int wg = (bid0 & 7) * 64 + (bid0 >> 3);
    const int bh = wg >> 2;
    const int qt = wg & 3;
    const int b = bh >> 3;
    const int h = bh & 7;

    if (tid < 64)
        lut_s[tid] = (tid < 49) ? lut[h * 49 + tid] * 1.4426950408889634f : -1e30f;

    const int r = lane & 15;
    const int g = lane >> 4;
    const int ko = g << 3;
    const int rowbase = qt * 128 + wave * 32;

    bf16x8 qf[2][2];
#pragma unroll
    for (int c = 0; c < 2; c++) {
        const bf16* qp = qb + ((size_t)bh * 512 + rowbase + c * 16 + r) * 64 + ko;
        qf[c][0] = *(const bf16x8*)qp;
        qf[c][1] = *(const bf16x8*)(qp + 32);
    }

    const bf16* kbb = kbuf + (size_t)bh * 512 * 64;
    const bf16* vbb = vtb + (size_t)bh * 64 * 512;
    const unsigned char* ip0 = idxg + ((size_t)b * 512 + rowbase + r) * 512;
    const unsigned char* ip1 = ip0 + (size_t)16 * 512;

    const int c0 = tid, c1 = 256 + tid;
    const int kr0 = c0 >> 3, ks0 = (c0 & 7) * 16;
    const int kr1 = c1 >> 3, ks1 = (c1 & 7) * 16;
    const bf16* ksrc0 = kbb + (size_t)kr0 * 64 + ((ks0 ^ ((kr0 & 7) << 4)) >> 1);
    const bf16* ksrc1 = kbb + (size_t)kr1 * 64 + ((ks1 ^ ((kr1 & 7) << 4)) >> 1);
    const bf16* vsrc0 = vbb + (size_t)kr0 * 512 + ((ks0 ^ ((kr0 & 7) << 4)) >> 1);
    const bf16* vsrc1 = vbb + (size_t)kr1 * 512 + ((ks1 ^ ((kr1 & 7) << 4)) >> 1);

    auto stage = [&](int buf, int s0) {
        async_ld16(&KT[buf][c0 * 8], ksrc0 + (size_t)s0 * 64);
        async_ld16(&KT[buf][c1 * 8], ksrc1 + (size_t)s0 * 64);
        async_ld16(&VT[buf][c0 * 8], vsrc0 + s0);
        async_ld16(&VT[buf][c1 * 8], vsrc1 + s0);
    };

    unsigned int idb[2][2][4];
    auto ldidx = [&](int par, int s0) {
#pragma unroll
        for (int nf = 0; nf < 4; nf++) {
            idb[par][0][nf] = *(const unsigned int*)(ip0 + s0 + nf * 16 + (g << 2));
            idb[par][1][nf] = *(const unsigned int*)(ip1 + s0 + nf * 16 + (g << 2));
        }
    };

    f32x4 o[2][4];
#pragma unroll
    for (int c = 0; c < 2; c++)
#pragma unroll
        for (int i = 0; i < 4; i++) o[c][i] = (f32x4){0.f, 0.f, 0.f, 0.f};
    float lsum[2] = {0.f, 0.f};

    const float QS = 0.125f * 1.4426950408889634f;

    stage(0, 0);
    ldidx(0, 0);
#pragma unroll
    for (int ti = 0; ti < 8; ti++) {
        const int buf = ti & 1;
        const int s0 = ti * 64;
        asm volatile("s_waitcnt vmcnt(0)" ::: "memory");
        __builtin_amdgcn_s_barrier();
        if (ti < 7) {
            stage(buf ^ 1, s0 + 64);
            ldidx((ti + 1) & 1, s0 + 64);
        }
        f32x4 sa[2][4];
        __builtin_amdgcn_s_setprio(1);
#pragma unroll
        for (int nf = 0; nf < 4; nf++) {
            const int row = nf * 16 + r;
            const int swz = (row & 7) << 4;
            bf16x8 kf0 = *(const bf16x8*)&KT[buf][row * 64 + (((g * 16) ^ swz) >> 1)];
            bf16x8 kf1 = *(const bf16x8*)&KT[buf][row * 64 + (((g * 16 + 64) ^ swz) >> 1)];
            sa[0][nf] = MFMA(kf0, qf[0][0], ((f32x4){0.f, 0.f, 0.f, 0.f}));
            sa[0][nf] = MFMA(kf1, qf[0][1], sa[0][nf]);
            sa[1][nf] = MFMA(kf0, qf[1][0], ((f32x4){0.f, 0.f, 0.f, 0.f}));
            sa[1][nf] = MFMA(kf1, qf[1][1], sa[1][nf]);
        }
        __builtin_amdgcn_s_setprio(0);
#pragma unroll
        for (int c = 0; c < 2; c++) {
            float ts = 0.f;
#pragma unroll
            for (int nf = 0; nf < 4; nf++) {
                unsigned int u = idb[ti & 1][c][nf];
                float p0 = exp2f(fmaf(sa[c][nf][0], QS, lut_s[u & 255]));
                float p1 = exp2f(fmaf(sa[c][nf][1], QS, lut_s[(u >> 8) & 255]));
                float p2 = exp2f(fmaf(sa[c][nf][2], QS, lut_s[(u >> 16) & 255]));
                float p3 = exp2f(fmaf(sa[c][nf][3], QS, lut_s[u >> 24]));
                ts += (p0 + p1) + (p2 + p3);
                bf16x4 pk = {(bf16)p0, (bf16)p1, (bf16)p2, (bf16)p3};
                *(bf16x4*)&P[wave][c][r][nf * 16 + (g << 2)] = pk;
            }
            lsum[c] += ts;
        }
        bf16x8 pf00 = *(const bf16x8*)&P[wave][0][r][ko];
        bf16x8 pf01 = *(const bf16x8*)&P[wave][0][r][32 + ko];
        bf16x8 pf10 = *(const bf16x8*)&P[wave][1][r][ko];
        bf16x8 pf11 = *(const bf16x8*)&P[wave][1][r][32 + ko];
        __builtin_amdgcn_s_setprio(1);
#pragma unroll
        for (int nf = 0; nf < 4; nf++) {
            const int row = nf * 16 + r;
            const int swz = (row & 7) << 4;
            bf16x8 vf0 = *(const bf16x8*)&VT[buf][row * 64 + (((g * 16) ^ swz) >> 1)];
            bf16x8 vf1 = *(const bf16x8*)&VT[buf][row * 64 + (((g * 16 + 64) ^ swz) >> 1)];
            o[0][nf] = MFMA(pf00, vf0, o[0][nf]);
            o[0][nf] = MFMA(pf01, vf1, o[0][nf]);
            o[1][nf] = MFMA(pf10, vf0, o[1][nf]);
            o[1][nf] = MFMA(pf11, vf1, o[1][nf]);
        }
        __builtin_amdgcn_s_setprio(0);
    }
#pragma unroll
    for (int c = 0; c < 2; c++) {
        float ls = lsum[c];
        ls += __shfl_xor(ls, 16);
        ls += __shfl_xor(ls, 32);
        float invl = 1.0f / ls;
#pragma unroll
        for (int reg = 0; reg < 4; reg++) {
            float il = __shfl(invl, (g << 2) + reg);
            int t = rowbase + c * 16 + (g << 2) + reg;
            if (t < 500) {
                bf16* yp = yb + ((size_t)(b * 500 + t)) * 512 + h * 64;
#pragma unroll
                for (int nf = 0; nf < 4; nf++) yp[nf * 16 + r] = (bf16)(o[c][nf][reg] * il);
            }
        }
    }
}

// ---------------- launch ----------------
extern "C" void kernel_launch(void* const* d_in, const int* in_sizes, int n_in,
                              void* d_out, int out_size, void* d_ws, size_t ws_size,
                              hipStream_t stream) {
    const float* x     = (const float*)d_in[0];
    const float* ct    = (const float*)d_in[1];
    const float* Wattn = (const float*)d_in[2];
    const float* battn = (const float*)d_in[3];
    const float* Wproj = (const float*)d_in[4];
    const float* bproj = (const float*)d_in[5];
    const float* lut   = (const float*)d_in[6];
    float* out = (float*)d_out;

    char* w = (char*)d_ws;
    bf16* xb   = (bf16*)w;                w += (size_t)8064 * 512 * 2;
    bf16* Wa_t = (bf16*)w;                w += (size_t)1536 * 512 * 2;
    bf16* Wp_t = (bf16*)w;                w += (size_t)512 * 512 * 2;
    bf16* qb   = (bf16*)w;                w += (size_t)16 * 8 * 512 * 64 * 2;
    bf16* kbuf = (bf16*)w;                w += (size_t)16 * 8 * 512 * 64 * 2;
    bf16* vtb  = (bf16*)w;                w += (size_t)16 * 8 * 64 * 512 * 2;
    unsigned char* idxb = (unsigned char*)w; w += (size_t)16 * 512 * 512;
    bf16* yb   = (bf16*)w;                w += (size_t)8064 * 512 * 2;

    prep_fused<<<dim3(14496), 256, 0, stream>>>(x, Wattn, Wproj, ct,
                                                xb, Wa_t, Wp_t, yb, qb, kbuf, vtb, idxb);

    gemm128<128, 2, 2, 0><<<dim3(12, 63), 256, 0, stream>>>(xb, Wa_t, battn, qb, kbuf, vtb, nullptr);

    attn_kernel<<<dim3(512), 256, 0, stream>>>(qb, kbuf, vtb, idxb, lut, yb);

    gemm128<64, 4, 1, 1><<<dim3(8, 63), 256, 0, stream>>>(yb, Wp_t, bproj, nullptr, nullptr, nullptr, out);
}